// Round 6
// baseline (159.895 us; speedup 1.0000x reference)
//
#include <hip/hip_runtime.h>
#include <stdint.h>

#define B_ 2
#define S_ 2048
#define D_ 1024
#define H_ 16
#define HD_ 64
#define K_ 64

typedef __attribute__((ext_vector_type(8))) __bf16 bf16x8v;
typedef __attribute__((ext_vector_type(4))) float f32x4;
typedef __attribute__((ext_vector_type(8))) unsigned short ushort8v;

#define GLD_LDS16(g, l)                                                        \
  __builtin_amdgcn_global_load_lds(                                            \
      (const __attribute__((address_space(1))) void*)(g),                      \
      (__attribute__((address_space(3))) void*)(l), 16, 0, 0)

__device__ __forceinline__ float bf2f(unsigned short u) {
  union { unsigned u32; float f; } c;
  c.u32 = ((unsigned)u) << 16;
  return c.f;
}
__device__ __forceinline__ unsigned short f2bf(float f) {
  union { float f; unsigned u; } c;
  c.f = f;
  unsigned u = c.u;
  u += 0x7fffu + ((u >> 16) & 1u);  // RNE (finite inputs)
  return (unsigned short)(u >> 16);
}

// ---------------- cast x (fp32 -> bf16), vectorized ----------------
__global__ __launch_bounds__(256) void cast_f32_bf16(
    const float4* __restrict__ in, ushort4* __restrict__ outp, int n4) {
  int i = blockIdx.x * 256 + threadIdx.x;
  if (i >= n4) return;
  float4 v = in[i];
  ushort4 o;
  o.x = f2bf(v.x); o.y = f2bf(v.y); o.z = f2bf(v.z); o.w = f2bf(v.w);
  outp[i] = o;
}

// ------------- transpose + cast weights: W (R x C) -> WT (C x R) bf16 -------------
__global__ __launch_bounds__(256) void transpose_cast(
    const float* __restrict__ W, unsigned short* __restrict__ WT, int R, int C) {
  __shared__ float tile[64][65];
  const int r0 = blockIdx.y * 64;
  const int c0 = blockIdx.x * 64;
  const int t = threadIdx.x;
#pragma unroll
  for (int i = 0; i < 16; ++i) {
    int idx = t + i * 256;
    int rr = idx >> 6, cc = idx & 63;
    tile[rr][cc] = W[(size_t)(r0 + rr) * C + c0 + cc];
  }
  __syncthreads();
#pragma unroll
  for (int i = 0; i < 16; ++i) {
    int idx = t + i * 256;
    int rr = idx >> 6, cc = idx & 63;  // rr: row of WT (= col of W)
    WT[(size_t)(c0 + rr) * R + r0 + cc] = f2bf(tile[cc][rr]);
  }
}

// ---------------- bf16 GEMM, 128x128 tile, m97 structure (r2 config) --------
template <bool OUT_F32>
__global__ __launch_bounds__(256) void gemm_bias(
    const unsigned short* __restrict__ A, const unsigned short* __restrict__ Bt,
    const float* __restrict__ bias, void* __restrict__ Cout,
    int M, int N, int Kd) {
  __shared__ unsigned short As[128 * 32];
  __shared__ unsigned short Bs[128 * 32];
  const int t = threadIdx.x;
  const int w = t >> 6;
  const int l = t & 63;
  const int m0 = blockIdx.y * 128;
  const int n0 = blockIdx.x * 128;
  const int wr = w >> 1, wc = w & 1;

  f32x4 acc[4][4] = {};

  const int srow = t >> 2;          // 0..63
  const int scol = (t & 3) * 8;     // 0,8,16,24
  char* asBase = (char*)As + w * 1024;
  char* bsBase = (char*)Bs + w * 1024;

  const int lr = l & 15;
  const int kh = (l >> 4) * 8;

  const int KT = Kd >> 5;
  for (int kt = 0; kt < KT; ++kt) {
    const int k0 = kt << 5;
    {
      const unsigned short* g0 = A + (size_t)(m0 + srow) * Kd + k0 + scol;
      const unsigned short* g1 = A + (size_t)(m0 + 64 + srow) * Kd + k0 + scol;
      GLD_LDS16(g0, asBase);
      GLD_LDS16(g1, asBase + 4096);
      const unsigned short* h0 = Bt + (size_t)(n0 + srow) * Kd + k0 + scol;
      const unsigned short* h1 = Bt + (size_t)(n0 + 64 + srow) * Kd + k0 + scol;
      GLD_LDS16(h0, bsBase);
      GLD_LDS16(h1, bsBase + 4096);
    }
    __syncthreads();
    bf16x8v af[4], bfv[4];
#pragma unroll
    for (int m = 0; m < 4; ++m)
      af[m] = *(const bf16x8v*)&As[(wr * 64 + m * 16 + lr) * 32 + kh];
#pragma unroll
    for (int n = 0; n < 4; ++n)
      bfv[n] = *(const bf16x8v*)&Bs[(wc * 64 + n * 16 + lr) * 32 + kh];
#pragma unroll
    for (int m = 0; m < 4; ++m)
#pragma unroll
      for (int n = 0; n < 4; ++n)
        acc[m][n] = __builtin_amdgcn_mfma_f32_16x16x32_bf16(af[m], bfv[n],
                                                            acc[m][n], 0, 0, 0);
    __syncthreads();
  }

  const int rbase = (l >> 4) * 4;
#pragma unroll
  for (int m = 0; m < 4; ++m) {
#pragma unroll
    for (int n = 0; n < 4; ++n) {
      const int gc = n0 + wc * 64 + n * 16 + lr;
      const float bv = bias[gc];
#pragma unroll
      for (int j = 0; j < 4; ++j) {
        const int gr = m0 + wr * 64 + m * 16 + rbase + j;
        float v = acc[m][n][j] + bv;
        if (OUT_F32)
          ((float*)Cout)[(size_t)gr * N + gc] = v;
        else
          ((unsigned short*)Cout)[(size_t)gr * N + gc] = f2bf(v);
      }
    }
  }
}

// ---------------- routed gather attention (v6: r2 layout + no-max softmax) --
// qkv: (B*S) x 3072 bf16 bits, interleaved [q|k|v] (r2's layout -- measured
// FETCH floor 154 MB vs 245-281 MB for split buffers).
// One block per (b,s); wave w: key-half kh2=w>>1 (32 keys), head-half hh=w&1.
// lane l covers dims [hh*512 + l*8, +8); 8 lanes/head, 3-step shfl reduce.
// No-max softmax (scores ~ N(0,1), raw fp32 exp safe, shift-invariant);
// p stays within the producing wave (LDS write+read, no extra barrier).
__global__ __launch_bounds__(256) void attn_kernel(
    const unsigned short* __restrict__ qkv, const int* __restrict__ routes,
    unsigned short* __restrict__ outp) {
  __shared__ float sc[16][68];       // p values; bank = (4*head + j) % 32
  __shared__ unsigned rtsoff[64];    // (b*S + r) * 3072
  __shared__ float pbuf[1024];       // cross-wave PV partials
  __shared__ float lbuf[16];         // cross-wave denom partials
  const int bs = blockIdx.x;
  const int b = bs >> 11;            // / S_
  const int s = bs & (S_ - 1);
  const int t = threadIdx.x;
  const int w = t >> 6, l = t & 63;
  const int kh2 = w >> 1, hh = w & 1;

  if (t < 64) {
    int r = routes[s * K_ + t];
    r = min(max(r, 0), S_ - 1);
    rtsoff[t] = (unsigned)(b * S_ + r) * 3072u;
  }
  __syncthreads();

  const unsigned colo = hh * 512 + l * 8;
  const int head = colo >> 6;

  float q[8];
  {
    ushort8v u = *(const ushort8v*)(qkv + (size_t)bs * 3072 + colo);
#pragma unroll
    for (int i = 0; i < 8; ++i) q[i] = bf2f(u[i]) * 0.125f;  // 1/sqrt(64)
  }

  const unsigned kofs = 1024u + colo;
  const unsigned vofs = 2048u + colo;
  const int jbase = kh2 * 32;

  // pass 1: scores -> p (exp, no max), K-gather only
  float lsum = 0.f;
#pragma unroll 4
  for (int j2 = 0; j2 < 32; ++j2) {
    const int j = jbase + j2;
    ushort8v ku = *(const ushort8v*)(qkv + (rtsoff[j] + kofs));
    float d = q[0] * bf2f(ku[0]);
#pragma unroll
    for (int i = 1; i < 8; ++i) d += q[i] * bf2f(ku[i]);
    d += __shfl_xor(d, 1);
    d += __shfl_xor(d, 2);
    d += __shfl_xor(d, 4);
    const float p = __expf(d);
    lsum += p;
    sc[head][j] = p;  // 8 lanes, same addr+value: broadcast write, same wave
  }

  __syncthreads();  // phase-separate K-gather and V-gather working sets

  // pass 2: PV, V-gather only (p read back by the same wave)
  float acc[8] = {};
#pragma unroll 4
  for (int j2 = 0; j2 < 32; ++j2) {
    const int j = jbase + j2;
    ushort8v vu = *(const ushort8v*)(qkv + (rtsoff[j] + vofs));
    const float pw = sc[head][j];
#pragma unroll
    for (int i = 0; i < 8; ++i) acc[i] += pw * bf2f(vu[i]);
  }

  if (kh2 == 1) {
    f32x4 a0 = {acc[0], acc[1], acc[2], acc[3]};
    f32x4 a1 = {acc[4], acc[5], acc[6], acc[7]};
    *(f32x4*)&pbuf[colo] = a0;
    *(f32x4*)&pbuf[colo + 4] = a1;
    if ((l & 7) == 0) lbuf[head] = lsum;
  }
  __syncthreads();
  if (kh2 == 0) {
    const float inv = 1.0f / (lsum + lbuf[head]);
    ushort8v o;
#pragma unroll
    for (int i = 0; i < 8; ++i) o[i] = f2bf((acc[i] + pbuf[colo + i]) * inv);
    *(ushort8v*)(outp + (size_t)bs * D_ + colo) = o;
  }
}

extern "C" void kernel_launch(void* const* d_in, const int* in_sizes, int n_in,
                              void* d_out, int out_size, void* d_ws,
                              size_t ws_size, hipStream_t stream) {
  const float* x = (const float*)d_in[0];
  const float* Wqkv = (const float*)d_in[1];
  const float* bqkv = (const float*)d_in[2];
  const float* Wproj = (const float*)d_in[3];
  const float* bproj = (const float*)d_in[4];
  const int* routes = (const int*)d_in[5];
  float* out = (float*)d_out;

  char* ws = (char*)d_ws;
  // r2 layout exactly
  unsigned short* x_bf = (unsigned short*)(ws);                    //  8,388,608
  unsigned short* wqkvT = (unsigned short*)(ws + 8388608);         //  6,291,456
  unsigned short* wprojT = (unsigned short*)(ws + 14680064);       //  2,097,152
  unsigned short* qkv = (unsigned short*)(ws + 16777216);          // 25,165,824
  unsigned short* aout = (unsigned short*)(ws + 41943040);         //  8,388,608

  {
    int n4 = (B_ * S_ * D_) / 4;
    cast_f32_bf16<<<n4 / 256, 256, 0, stream>>>((const float4*)x,
                                                (ushort4*)x_bf, n4);
  }
  transpose_cast<<<dim3(3 * D_ / 64, D_ / 64), 256, 0, stream>>>(Wqkv, wqkvT,
                                                                 D_, 3 * D_);
  transpose_cast<<<dim3(D_ / 64, D_ / 64), 256, 0, stream>>>(Wproj, wprojT, D_,
                                                             D_);
  gemm_bias<false><<<dim3(3 * D_ / 128, B_ * S_ / 128), 256, 0, stream>>>(
      x_bf, wqkvT, bqkv, qkv, B_ * S_, 3 * D_, D_);
  attn_kernel<<<B_ * S_, 256, 0, stream>>>(qkv, routes, aout);
  gemm_bias<true><<<dim3(D_ / 128, B_ * S_ / 128), 256, 0, stream>>>(
      aout, wprojT, bproj, out, B_ * S_, D_, D_);
}

// Round 7
// 157.540 us; speedup vs baseline: 1.0149x; 1.0149x over previous
//
#include <hip/hip_runtime.h>
#include <stdint.h>

#define B_ 2
#define S_ 2048
#define D_ 1024
#define H_ 16
#define HD_ 64
#define K_ 64

typedef __attribute__((ext_vector_type(8))) __bf16 bf16x8v;
typedef __attribute__((ext_vector_type(4))) float f32x4;
typedef __attribute__((ext_vector_type(8))) unsigned short ushort8v;

#define GLD_LDS16(g, l)                                                        \
  __builtin_amdgcn_global_load_lds(                                            \
      (const __attribute__((address_space(1))) void*)(g),                      \
      (__attribute__((address_space(3))) void*)(l), 16, 0, 0)

__device__ __forceinline__ float bf2f(unsigned short u) {
  union { unsigned u32; float f; } c;
  c.u32 = ((unsigned)u) << 16;
  return c.f;
}
__device__ __forceinline__ unsigned short f2bf(float f) {
  union { float f; unsigned u; } c;
  c.f = f;
  unsigned u = c.u;
  u += 0x7fffu + ((u >> 16) & 1u);  // RNE (finite inputs)
  return (unsigned short)(u >> 16);
}

// ---------------- cast x (fp32 -> bf16), vectorized ----------------
__global__ __launch_bounds__(256) void cast_f32_bf16(
    const float4* __restrict__ in, ushort4* __restrict__ outp, int n4) {
  int i = blockIdx.x * 256 + threadIdx.x;
  if (i >= n4) return;
  float4 v = in[i];
  ushort4 o;
  o.x = f2bf(v.x); o.y = f2bf(v.y); o.z = f2bf(v.z); o.w = f2bf(v.w);
  outp[i] = o;
}

// ------------- transpose + cast weights: W (R x C) -> WT (C x R) bf16 -------------
__global__ __launch_bounds__(256) void transpose_cast(
    const float* __restrict__ W, unsigned short* __restrict__ WT, int R, int C) {
  __shared__ float tile[64][65];
  const int r0 = blockIdx.y * 64;
  const int c0 = blockIdx.x * 64;
  const int t = threadIdx.x;
#pragma unroll
  for (int i = 0; i < 16; ++i) {
    int idx = t + i * 256;
    int rr = idx >> 6, cc = idx & 63;
    tile[rr][cc] = W[(size_t)(r0 + rr) * C + c0 + cc];
  }
  __syncthreads();
#pragma unroll
  for (int i = 0; i < 16; ++i) {
    int idx = t + i * 256;
    int rr = idx >> 6, cc = idx & 63;  // rr: row of WT (= col of W)
    WT[(size_t)(c0 + rr) * R + r0 + cc] = f2bf(tile[cc][rr]);
  }
}

// ---------------- bf16 GEMM, 128x128 tile, m97 structure (proj) ----------------
template <bool OUT_F32>
__global__ __launch_bounds__(256) void gemm_bias(
    const unsigned short* __restrict__ A, const unsigned short* __restrict__ Bt,
    const float* __restrict__ bias, void* __restrict__ Cout,
    int M, int N, int Kd) {
  __shared__ unsigned short As[128 * 32];
  __shared__ unsigned short Bs[128 * 32];
  const int t = threadIdx.x;
  const int w = t >> 6;
  const int l = t & 63;
  const int m0 = blockIdx.y * 128;
  const int n0 = blockIdx.x * 128;
  const int wr = w >> 1, wc = w & 1;

  f32x4 acc[4][4] = {};

  const int srow = t >> 2;
  const int scol = (t & 3) * 8;
  char* asBase = (char*)As + w * 1024;
  char* bsBase = (char*)Bs + w * 1024;

  const int lr = l & 15;
  const int kh = (l >> 4) * 8;

  const int KT = Kd >> 5;
  for (int kt = 0; kt < KT; ++kt) {
    const int k0 = kt << 5;
    {
      const unsigned short* g0 = A + (size_t)(m0 + srow) * Kd + k0 + scol;
      const unsigned short* g1 = A + (size_t)(m0 + 64 + srow) * Kd + k0 + scol;
      GLD_LDS16(g0, asBase);
      GLD_LDS16(g1, asBase + 4096);
      const unsigned short* h0 = Bt + (size_t)(n0 + srow) * Kd + k0 + scol;
      const unsigned short* h1 = Bt + (size_t)(n0 + 64 + srow) * Kd + k0 + scol;
      GLD_LDS16(h0, bsBase);
      GLD_LDS16(h1, bsBase + 4096);
    }
    __syncthreads();
    bf16x8v af[4], bfv[4];
#pragma unroll
    for (int m = 0; m < 4; ++m)
      af[m] = *(const bf16x8v*)&As[(wr * 64 + m * 16 + lr) * 32 + kh];
#pragma unroll
    for (int n = 0; n < 4; ++n)
      bfv[n] = *(const bf16x8v*)&Bs[(wc * 64 + n * 16 + lr) * 32 + kh];
#pragma unroll
    for (int m = 0; m < 4; ++m)
#pragma unroll
      for (int n = 0; n < 4; ++n)
        acc[m][n] = __builtin_amdgcn_mfma_f32_16x16x32_bf16(af[m], bfv[n],
                                                            acc[m][n], 0, 0, 0);
    __syncthreads();
  }

  const int rbase = (l >> 4) * 4;
#pragma unroll
  for (int m = 0; m < 4; ++m) {
#pragma unroll
    for (int n = 0; n < 4; ++n) {
      const int gc = n0 + wc * 64 + n * 16 + lr;
      const float bv = bias[gc];
#pragma unroll
      for (int j = 0; j < 4; ++j) {
        const int gr = m0 + wr * 64 + m * 16 + rbase + j;
        float v = acc[m][n][j] + bv;
        if (OUT_F32)
          ((float*)Cout)[(size_t)gr * N + gc] = v;
        else
          ((unsigned short*)Cout)[(size_t)gr * N + gc] = f2bf(v);
      }
    }
  }
}

// ------------- qkv GEMM: 256x256 tile, BK=64, 8 waves, phase-split ----------
// M=4096, N=3072, K=1024 fixed. Linear LDS (m198 config), counted vmcnt,
// raw s_barrier, setprio around MFMA clusters. Double-buffered K-tiles.
__global__ __launch_bounds__(512, 2) void gemm_qkv_256(
    const unsigned short* __restrict__ A, const unsigned short* __restrict__ Bt,
    const float* __restrict__ bias, unsigned short* __restrict__ Cout) {
  __shared__ unsigned short As2[2][256 * 64];  // 64 KB
  __shared__ unsigned short Bs2[2][256 * 64];  // 64 KB
  const int t = threadIdx.x;
  const int w = t >> 6, l = t & 63;
  const int wr = w >> 2, wc = w & 3;          // 2 x 4 wave grid
  const int m0 = blockIdx.y * 256, n0 = blockIdx.x * 256;

  f32x4 acc[8][4] = {};

  // staging: granule g = w*64 + l + i*512 -> row g/8, col (g&7)*8 of the tile
  const int srow = w * 8 + (l >> 3);   // + i*64
  const int scol = (l & 7) * 8;
  const int ldsoff = w * 1024;         // + i*8192 (bytes); lane*16 implicit

#define STAGE_A(kt, buf)                                                       \
  {                                                                            \
    _Pragma("unroll") for (int i = 0; i < 4; ++i)                              \
        GLD_LDS16(A + (size_t)(m0 + srow + i * 64) * 1024 + (kt) * 64 + scol,  \
                  (char*)As2[buf] + ldsoff + i * 8192);                        \
  }
#define STAGE_B(kt, buf)                                                       \
  {                                                                            \
    _Pragma("unroll") for (int i = 0; i < 4; ++i)                              \
        GLD_LDS16(Bt + (size_t)(n0 + srow + i * 64) * 1024 + (kt) * 64 + scol, \
                  (char*)Bs2[buf] + ldsoff + i * 8192);                        \
  }

  const int lr = l & 15, kq = (l >> 4) * 8;
  const int KT = 16;  // 1024 / 64

  // prologue: stage kt=0 and kt=1 (B then A each, 8 loads per K-tile)
  STAGE_B(0, 0); STAGE_A(0, 0);
  STAGE_B(1, 1); STAGE_A(1, 1);

  bf16x8v a4[4][2], b01[2][2], b23[2][2];

  for (int kt = 0; kt < KT; ++kt) {
    const int cur = kt & 1;
    if (kt < KT - 1)
      asm volatile("s_waitcnt vmcnt(8)" ::: "memory");
    else
      asm volatile("s_waitcnt vmcnt(0)" ::: "memory");
    __builtin_amdgcn_s_barrier();  // buf[cur] ready block-wide

    // ---- phase 0: A m0-3 + B n0-1, MFMA m0-3 x n0-1 ----
#pragma unroll
    for (int m = 0; m < 4; ++m)
#pragma unroll
      for (int ks = 0; ks < 2; ++ks)
        a4[m][ks] = *(const bf16x8v*)&As2[cur][(wr * 128 + m * 16 + lr) * 64 +
                                              ks * 32 + kq];
#pragma unroll
    for (int n = 0; n < 2; ++n)
#pragma unroll
      for (int ks = 0; ks < 2; ++ks)
        b01[n][ks] = *(const bf16x8v*)&Bs2[cur][(wc * 64 + n * 16 + lr) * 64 +
                                               ks * 32 + kq];
    __builtin_amdgcn_s_setprio(1);
#pragma unroll
    for (int m = 0; m < 4; ++m)
#pragma unroll
      for (int n = 0; n < 2; ++n)
#pragma unroll
        for (int ks = 0; ks < 2; ++ks)
          acc[m][n] = __builtin_amdgcn_mfma_f32_16x16x32_bf16(
              a4[m][ks], b01[n][ks], acc[m][n], 0, 0, 0);
    __builtin_amdgcn_s_setprio(0);

    // ---- phase 1: B n2-3, MFMA m0-3 x n2-3 ----
#pragma unroll
    for (int n = 0; n < 2; ++n)
#pragma unroll
      for (int ks = 0; ks < 2; ++ks)
        b23[n][ks] = *(const bf16x8v*)&Bs2[cur][(wc * 64 + (n + 2) * 16 + lr) *
                                                   64 + ks * 32 + kq];
    __builtin_amdgcn_s_setprio(1);
#pragma unroll
    for (int m = 0; m < 4; ++m)
#pragma unroll
      for (int n = 0; n < 2; ++n)
#pragma unroll
        for (int ks = 0; ks < 2; ++ks)
          acc[m][n + 2] = __builtin_amdgcn_mfma_f32_16x16x32_bf16(
              a4[m][ks], b23[n][ks], acc[m][n + 2], 0, 0, 0);
    __builtin_amdgcn_s_setprio(0);

    __builtin_amdgcn_s_barrier();  // all waves done with B region of buf[cur]

    // ---- phase 2: stage B(kt+2), A m4-7, MFMA m4-7 x n2-3 ----
    if (kt + 2 < KT) STAGE_B(kt + 2, cur);
#pragma unroll
    for (int m = 0; m < 4; ++m)
#pragma unroll
      for (int ks = 0; ks < 2; ++ks)
        a4[m][ks] = *(const bf16x8v*)&As2[cur][(wr * 128 + (m + 4) * 16 + lr) *
                                                  64 + ks * 32 + kq];
    __builtin_amdgcn_s_setprio(1);
#pragma unroll
    for (int m = 0; m < 4; ++m)
#pragma unroll
      for (int n = 0; n < 2; ++n)
#pragma unroll
        for (int ks = 0; ks < 2; ++ks)
          acc[m + 4][n + 2] = __builtin_amdgcn_mfma_f32_16x16x32_bf16(
              a4[m][ks], b23[n][ks], acc[m + 4][n + 2], 0, 0, 0);
    __builtin_amdgcn_s_setprio(0);

    __builtin_amdgcn_s_barrier();  // all waves done with A region of buf[cur]

    // ---- phase 3: stage A(kt+2), MFMA m4-7 x n0-1 (regs only) ----
    if (kt + 2 < KT) STAGE_A(kt + 2, cur);
    __builtin_amdgcn_s_setprio(1);
#pragma unroll
    for (int m = 0; m < 4; ++m)
#pragma unroll
      for (int n = 0; n < 2; ++n)
#pragma unroll
        for (int ks = 0; ks < 2; ++ks)
          acc[m + 4][n] = __builtin_amdgcn_mfma_f32_16x16x32_bf16(
              a4[m][ks], b01[n][ks], acc[m + 4][n], 0, 0, 0);
    __builtin_amdgcn_s_setprio(0);
  }

  const int rb = (l >> 4) * 4;
#pragma unroll
  for (int m = 0; m < 8; ++m) {
#pragma unroll
    for (int n = 0; n < 4; ++n) {
      const int gc = n0 + wc * 64 + n * 16 + lr;
      const float bv = bias[gc];
#pragma unroll
      for (int j = 0; j < 4; ++j) {
        const int gr = m0 + wr * 128 + m * 16 + rb + j;
        Cout[(size_t)gr * 3072 + gc] = f2bf(acc[m][n][j] + bv);
      }
    }
  }
#undef STAGE_A
#undef STAGE_B
}

// ---------------- routed gather attention (v2-exact, round-2 67us config) --
__global__ __launch_bounds__(256) void attn_kernel(
    const unsigned short* __restrict__ qkv, const int* __restrict__ routes,
    unsigned short* __restrict__ outp) {
  __shared__ float sc[16][68];       // padded: bank = (4*head + j) % 32
  __shared__ unsigned rtsoff[64];    // precomputed (b*S + r) * 3072
  __shared__ float pbuf[1024];       // cross-wave PV partials
  const int bs = blockIdx.x;
  const int b = bs >> 11;            // / S_
  const int s = bs & (S_ - 1);
  const int t = threadIdx.x;
  const int w = t >> 6, l = t & 63;
  const int kh2 = w >> 1, hh = w & 1;

  if (t < 64) {
    int r = routes[s * K_ + t];
    r = min(max(r, 0), S_ - 1);
    rtsoff[t] = (unsigned)(b * S_ + r) * 3072u;
  }
  __syncthreads();

  const unsigned colo = hh * 512 + l * 8;
  const int head = colo >> 6;
  const size_t rowbase = (size_t)bs * 3072;

  float q[8];
  {
    ushort8v u = *(const ushort8v*)(qkv + rowbase + colo);
#pragma unroll
    for (int i = 0; i < 8; ++i) q[i] = bf2f(u[i]) * 0.125f;  // 1/sqrt(64)
  }

  const unsigned kofs = 1024u + colo;
  const unsigned vofs = 2048u + colo;
  const int jbase = kh2 * 32;

  // scores
#pragma unroll 4
  for (int j2 = 0; j2 < 32; ++j2) {
    const int j = jbase + j2;
    ushort8v u = *(const ushort8v*)(qkv + (rtsoff[j] + kofs));
    float d = q[0] * bf2f(u[0]);
#pragma unroll
    for (int i = 1; i < 8; ++i) d += q[i] * bf2f(u[i]);
    d += __shfl_xor(d, 1);
    d += __shfl_xor(d, 2);
    d += __shfl_xor(d, 4);
    if ((l & 7) == 0) sc[head][j] = d;
  }
  __syncthreads();

  // softmax over K=64, 16 threads per head
  {
    const int h = t >> 4;
    const int l2 = t & 15;
    float v0 = sc[h][l2], v1 = sc[h][l2 + 16], v2 = sc[h][l2 + 32],
          v3 = sc[h][l2 + 48];
    float m = fmaxf(fmaxf(v0, v1), fmaxf(v2, v3));
    m = fmaxf(m, __shfl_xor(m, 1));
    m = fmaxf(m, __shfl_xor(m, 2));
    m = fmaxf(m, __shfl_xor(m, 4));
    m = fmaxf(m, __shfl_xor(m, 8));
    v0 = __expf(v0 - m); v1 = __expf(v1 - m);
    v2 = __expf(v2 - m); v3 = __expf(v3 - m);
    float ss = v0 + v1 + v2 + v3;
    ss += __shfl_xor(ss, 1);
    ss += __shfl_xor(ss, 2);
    ss += __shfl_xor(ss, 4);
    ss += __shfl_xor(ss, 8);
    float inv = 1.0f / ss;
    sc[h][l2] = v0 * inv;
    sc[h][l2 + 16] = v1 * inv;
    sc[h][l2 + 32] = v2 * inv;
    sc[h][l2 + 48] = v3 * inv;
  }
  __syncthreads();

  // PV
  float acc[8] = {};
#pragma unroll 4
  for (int j2 = 0; j2 < 32; ++j2) {
    const int j = jbase + j2;
    ushort8v u = *(const ushort8v*)(qkv + (rtsoff[j] + vofs));
    const float p = sc[head][j];
#pragma unroll
    for (int i = 0; i < 8; ++i) acc[i] += p * bf2f(u[i]);
  }

  if (kh2 == 1) {
    f32x4 a0 = {acc[0], acc[1], acc[2], acc[3]};
    f32x4 a1 = {acc[4], acc[5], acc[6], acc[7]};
    *(f32x4*)&pbuf[colo] = a0;
    *(f32x4*)&pbuf[colo + 4] = a1;
  }
  __syncthreads();
  if (kh2 == 0) {
    ushort8v o;
#pragma unroll
    for (int i = 0; i < 8; ++i) o[i] = f2bf(acc[i] + pbuf[colo + i]);
    *(ushort8v*)(outp + (size_t)bs * D_ + colo) = o;
  }
}

extern "C" void kernel_launch(void* const* d_in, const int* in_sizes, int n_in,
                              void* d_out, int out_size, void* d_ws,
                              size_t ws_size, hipStream_t stream) {
  const float* x = (const float*)d_in[0];
  const float* Wqkv = (const float*)d_in[1];
  const float* bqkv = (const float*)d_in[2];
  const float* Wproj = (const float*)d_in[3];
  const float* bproj = (const float*)d_in[4];
  const int* routes = (const int*)d_in[5];
  float* out = (float*)d_out;

  char* ws = (char*)d_ws;
  unsigned short* x_bf = (unsigned short*)(ws);                    //  8,388,608
  unsigned short* wqkvT = (unsigned short*)(ws + 8388608);         //  6,291,456
  unsigned short* wprojT = (unsigned short*)(ws + 14680064);       //  2,097,152
  unsigned short* qkv = (unsigned short*)(ws + 16777216);          // 25,165,824
  unsigned short* aout = (unsigned short*)(ws + 41943040);         //  8,388,608

  {
    int n4 = (B_ * S_ * D_) / 4;
    cast_f32_bf16<<<n4 / 256, 256, 0, stream>>>((const float4*)x,
                                                (ushort4*)x_bf, n4);
  }
  transpose_cast<<<dim3(3 * D_ / 64, D_ / 64), 256, 0, stream>>>(Wqkv, wqkvT,
                                                                 D_, 3 * D_);
  transpose_cast<<<dim3(D_ / 64, D_ / 64), 256, 0, stream>>>(Wproj, wprojT, D_,
                                                             D_);
  // qkv = x @ Wqkv + b : 256^2 phase-split kernel, grid 12 x 16 = 192 blocks
  gemm_qkv_256<<<dim3(3 * D_ / 256, B_ * S_ / 256), 512, 0, stream>>>(
      x_bf, wqkvT, bqkv, qkv);
  attn_kernel<<<B_ * S_, 256, 0, stream>>>(qkv, routes, aout);
  gemm_bias<true><<<dim3(D_ / 128, B_ * S_ / 128), 256, 0, stream>>>(
      aout, wprojT, bproj, out, B_ * S_, D_, D_);
}

// Round 8
// 143.159 us; speedup vs baseline: 1.1169x; 1.1005x over previous
//
#include <hip/hip_runtime.h>
#include <stdint.h>

#define B_ 2
#define S_ 2048
#define D_ 1024
#define H_ 16
#define HD_ 64
#define K_ 64

typedef __attribute__((ext_vector_type(8))) __bf16 bf16x8v;
typedef __attribute__((ext_vector_type(4))) float f32x4;
typedef __attribute__((ext_vector_type(8))) unsigned short ushort8v;

#define GLD_LDS16(g, l)                                                        \
  __builtin_amdgcn_global_load_lds(                                            \
      (const __attribute__((address_space(1))) void*)(g),                      \
      (__attribute__((address_space(3))) void*)(l), 16, 0, 0)

__device__ __forceinline__ float bf2f(unsigned short u) {
  union { unsigned u32; float f; } c;
  c.u32 = ((unsigned)u) << 16;
  return c.f;
}
__device__ __forceinline__ unsigned short f2bf(float f) {
  union { float f; unsigned u; } c;
  c.f = f;
  unsigned u = c.u;
  u += 0x7fffu + ((u >> 16) & 1u);  // RNE (finite inputs)
  return (unsigned short)(u >> 16);
}

// ------------- fused prep: cast x + transpose-cast both weights -------------
// grid = 5120 blocks x 256 threads, block-uniform branch:
//   [0,4096):    cast x (f32 -> bf16), 1024 float4 per block
//   [4096,4864): Wqkv transpose tile (48 x 16 tiles of 64x64)
//   [4864,5120): Wproj transpose tile (16 x 16 tiles of 64x64)
__global__ __launch_bounds__(256) void prep_fused(
    const float* __restrict__ x, unsigned short* __restrict__ x_bf,
    const float* __restrict__ Wqkv, unsigned short* __restrict__ wqkvT,
    const float* __restrict__ Wproj, unsigned short* __restrict__ wprojT) {
  __shared__ float tile[64][65];
  const int bid = blockIdx.x;
  const int t = threadIdx.x;

  if (bid < 4096) {
    // cast path
    const int i = bid * 256 + t;  // float4 index, n4 = 1048576
    float4 v = ((const float4*)x)[i];
    ushort4 o;
    o.x = f2bf(v.x); o.y = f2bf(v.y); o.z = f2bf(v.z); o.w = f2bf(v.w);
    ((ushort4*)x_bf)[i] = o;
    return;
  }

  const float* W;
  unsigned short* WT;
  int R, C, bx, by;
  if (bid < 4096 + 768) {
    const int b2 = bid - 4096;
    W = Wqkv; WT = wqkvT; R = D_; C = 3 * D_;
    by = b2 / 48; bx = b2 - by * 48;
  } else {
    const int b3 = bid - 4096 - 768;
    W = Wproj; WT = wprojT; R = D_; C = D_;
    by = b3 >> 4; bx = b3 & 15;
  }
  const int r0 = by * 64;
  const int c0 = bx * 64;
#pragma unroll
  for (int i = 0; i < 16; ++i) {
    int idx = t + i * 256;
    int rr = idx >> 6, cc = idx & 63;
    tile[rr][cc] = W[(size_t)(r0 + rr) * C + c0 + cc];
  }
  __syncthreads();
#pragma unroll
  for (int i = 0; i < 16; ++i) {
    int idx = t + i * 256;
    int rr = idx >> 6, cc = idx & 63;  // rr: row of WT (= col of W)
    WT[(size_t)(c0 + rr) * R + r0 + cc] = f2bf(tile[cc][rr]);
  }
}

// ---------------- bf16 GEMM, 128x128 tile, m97 structure (r2-exact) ---------
template <bool OUT_F32>
__global__ __launch_bounds__(256) void gemm_bias(
    const unsigned short* __restrict__ A, const unsigned short* __restrict__ Bt,
    const float* __restrict__ bias, void* __restrict__ Cout,
    int M, int N, int Kd) {
  __shared__ unsigned short As[128 * 32];
  __shared__ unsigned short Bs[128 * 32];
  const int t = threadIdx.x;
  const int w = t >> 6;
  const int l = t & 63;
  const int m0 = blockIdx.y * 128;
  const int n0 = blockIdx.x * 128;
  const int wr = w >> 1, wc = w & 1;

  f32x4 acc[4][4] = {};

  const int srow = t >> 2;          // 0..63
  const int scol = (t & 3) * 8;     // 0,8,16,24
  char* asBase = (char*)As + w * 1024;
  char* bsBase = (char*)Bs + w * 1024;

  const int lr = l & 15;
  const int kh = (l >> 4) * 8;

  const int KT = Kd >> 5;
  for (int kt = 0; kt < KT; ++kt) {
    const int k0 = kt << 5;
    {
      const unsigned short* g0 = A + (size_t)(m0 + srow) * Kd + k0 + scol;
      const unsigned short* g1 = A + (size_t)(m0 + 64 + srow) * Kd + k0 + scol;
      GLD_LDS16(g0, asBase);
      GLD_LDS16(g1, asBase + 4096);
      const unsigned short* h0 = Bt + (size_t)(n0 + srow) * Kd + k0 + scol;
      const unsigned short* h1 = Bt + (size_t)(n0 + 64 + srow) * Kd + k0 + scol;
      GLD_LDS16(h0, bsBase);
      GLD_LDS16(h1, bsBase + 4096);
    }
    __syncthreads();
    bf16x8v af[4], bfv[4];
#pragma unroll
    for (int m = 0; m < 4; ++m)
      af[m] = *(const bf16x8v*)&As[(wr * 64 + m * 16 + lr) * 32 + kh];
#pragma unroll
    for (int n = 0; n < 4; ++n)
      bfv[n] = *(const bf16x8v*)&Bs[(wc * 64 + n * 16 + lr) * 32 + kh];
#pragma unroll
    for (int m = 0; m < 4; ++m)
#pragma unroll
      for (int n = 0; n < 4; ++n)
        acc[m][n] = __builtin_amdgcn_mfma_f32_16x16x32_bf16(af[m], bfv[n],
                                                            acc[m][n], 0, 0, 0);
    __syncthreads();
  }

  const int rbase = (l >> 4) * 4;
#pragma unroll
  for (int m = 0; m < 4; ++m) {
#pragma unroll
    for (int n = 0; n < 4; ++n) {
      const int gc = n0 + wc * 64 + n * 16 + lr;
      const float bv = bias[gc];
#pragma unroll
      for (int j = 0; j < 4; ++j) {
        const int gr = m0 + wr * 64 + m * 16 + rbase + j;
        float v = acc[m][n][j] + bv;
        if (OUT_F32)
          ((float*)Cout)[(size_t)gr * N + gc] = v;
        else
          ((unsigned short*)Cout)[(size_t)gr * N + gc] = f2bf(v);
      }
    }
  }
}

// ---------------- routed gather attention (v2-exact, 67us / 154MB config) ---
__global__ __launch_bounds__(256) void attn_kernel(
    const unsigned short* __restrict__ qkv, const int* __restrict__ routes,
    unsigned short* __restrict__ outp) {
  __shared__ float sc[16][68];       // padded: bank = (4*head + j) % 32
  __shared__ unsigned rtsoff[64];    // precomputed (b*S + r) * 3072
  __shared__ float pbuf[1024];       // cross-wave PV partials
  const int bs = blockIdx.x;
  const int b = bs >> 11;            // / S_
  const int s = bs & (S_ - 1);
  const int t = threadIdx.x;
  const int w = t >> 6, l = t & 63;
  const int kh2 = w >> 1, hh = w & 1;

  if (t < 64) {
    int r = routes[s * K_ + t];
    r = min(max(r, 0), S_ - 1);
    rtsoff[t] = (unsigned)(b * S_ + r) * 3072u;
  }
  __syncthreads();

  const unsigned colo = hh * 512 + l * 8;
  const int head = colo >> 6;
  const size_t rowbase = (size_t)bs * 3072;

  float q[8];
  {
    ushort8v u = *(const ushort8v*)(qkv + rowbase + colo);
#pragma unroll
    for (int i = 0; i < 8; ++i) q[i] = bf2f(u[i]) * 0.125f;  // 1/sqrt(64)
  }

  const unsigned kofs = 1024u + colo;
  const unsigned vofs = 2048u + colo;
  const int jbase = kh2 * 32;

  // scores
#pragma unroll 4
  for (int j2 = 0; j2 < 32; ++j2) {
    const int j = jbase + j2;
    ushort8v u = *(const ushort8v*)(qkv + (rtsoff[j] + kofs));
    float d = q[0] * bf2f(u[0]);
#pragma unroll
    for (int i = 1; i < 8; ++i) d += q[i] * bf2f(u[i]);
    d += __shfl_xor(d, 1);
    d += __shfl_xor(d, 2);
    d += __shfl_xor(d, 4);
    if ((l & 7) == 0) sc[head][j] = d;
  }
  __syncthreads();

  // softmax over K=64, 16 threads per head
  {
    const int h = t >> 4;
    const int l2 = t & 15;
    float v0 = sc[h][l2], v1 = sc[h][l2 + 16], v2 = sc[h][l2 + 32],
          v3 = sc[h][l2 + 48];
    float m = fmaxf(fmaxf(v0, v1), fmaxf(v2, v3));
    m = fmaxf(m, __shfl_xor(m, 1));
    m = fmaxf(m, __shfl_xor(m, 2));
    m = fmaxf(m, __shfl_xor(m, 4));
    m = fmaxf(m, __shfl_xor(m, 8));
    v0 = __expf(v0 - m); v1 = __expf(v1 - m);
    v2 = __expf(v2 - m); v3 = __expf(v3 - m);
    float ss = v0 + v1 + v2 + v3;
    ss += __shfl_xor(ss, 1);
    ss += __shfl_xor(ss, 2);
    ss += __shfl_xor(ss, 4);
    ss += __shfl_xor(ss, 8);
    float inv = 1.0f / ss;
    sc[h][l2] = v0 * inv;
    sc[h][l2 + 16] = v1 * inv;
    sc[h][l2 + 32] = v2 * inv;
    sc[h][l2 + 48] = v3 * inv;
  }
  __syncthreads();

  // PV
  float acc[8] = {};
#pragma unroll 4
  for (int j2 = 0; j2 < 32; ++j2) {
    const int j = jbase + j2;
    ushort8v u = *(const ushort8v*)(qkv + (rtsoff[j] + vofs));
    const float p = sc[head][j];
#pragma unroll
    for (int i = 0; i < 8; ++i) acc[i] += p * bf2f(u[i]);
  }

  if (kh2 == 1) {
    f32x4 a0 = {acc[0], acc[1], acc[2], acc[3]};
    f32x4 a1 = {acc[4], acc[5], acc[6], acc[7]};
    *(f32x4*)&pbuf[colo] = a0;
    *(f32x4*)&pbuf[colo + 4] = a1;
  }
  __syncthreads();
  if (kh2 == 0) {
    ushort8v o;
#pragma unroll
    for (int i = 0; i < 8; ++i) o[i] = f2bf(acc[i] + pbuf[colo + i]);
    *(ushort8v*)(outp + (size_t)bs * D_ + colo) = o;
  }
}

extern "C" void kernel_launch(void* const* d_in, const int* in_sizes, int n_in,
                              void* d_out, int out_size, void* d_ws,
                              size_t ws_size, hipStream_t stream) {
  const float* x = (const float*)d_in[0];
  const float* Wqkv = (const float*)d_in[1];
  const float* bqkv = (const float*)d_in[2];
  const float* Wproj = (const float*)d_in[3];
  const float* bproj = (const float*)d_in[4];
  const int* routes = (const int*)d_in[5];
  float* out = (float*)d_out;

  char* ws = (char*)d_ws;
  // r2 layout exactly
  unsigned short* x_bf = (unsigned short*)(ws);                    //  8,388,608
  unsigned short* wqkvT = (unsigned short*)(ws + 8388608);         //  6,291,456
  unsigned short* wprojT = (unsigned short*)(ws + 14680064);       //  2,097,152
  unsigned short* qkv = (unsigned short*)(ws + 16777216);          // 25,165,824
  unsigned short* aout = (unsigned short*)(ws + 41943040);         //  8,388,608

  // fused prep: cast (4096 blocks) + Wqkv^T (768) + Wproj^T (256)
  prep_fused<<<5120, 256, 0, stream>>>(x, x_bf, Wqkv, wqkvT, Wproj, wprojT);

  gemm_bias<false><<<dim3(3 * D_ / 128, B_ * S_ / 128), 256, 0, stream>>>(
      x_bf, wqkvT, bqkv, qkv, B_ * S_, 3 * D_, D_);
  attn_kernel<<<B_ * S_, 256, 0, stream>>>(qkv, routes, aout);
  gemm_bias<true><<<dim3(D_ / 128, B_ * S_ / 128), 256, 0, stream>>>(
      aout, wprojT, bproj, out, B_ * S_, D_, D_);
}

// Round 9
// 135.972 us; speedup vs baseline: 1.1759x; 1.0529x over previous
//
#include <hip/hip_runtime.h>
#include <stdint.h>

#define B_ 2
#define S_ 2048
#define D_ 1024
#define H_ 16
#define HD_ 64
#define K_ 64

typedef __attribute__((ext_vector_type(8))) __bf16 bf16x8v;
typedef __attribute__((ext_vector_type(4))) float f32x4;
typedef __attribute__((ext_vector_type(8))) unsigned short ushort8v;

#define GLD_LDS16(g, l)                                                        \
  __builtin_amdgcn_global_load_lds(                                            \
      (const __attribute__((address_space(1))) void*)(g),                      \
      (__attribute__((address_space(3))) void*)(l), 16, 0, 0)

__device__ __forceinline__ float bf2f(unsigned short u) {
  union { unsigned u32; float f; } c;
  c.u32 = ((unsigned)u) << 16;
  return c.f;
}
__device__ __forceinline__ unsigned short f2bf(float f) {
  union { float f; unsigned u; } c;
  c.f = f;
  unsigned u = c.u;
  u += 0x7fffu + ((u >> 16) & 1u);  // RNE (finite inputs)
  return (unsigned short)(u >> 16);
}

// ------------- fused prep: cast x + transpose-cast both weights -------------
__global__ __launch_bounds__(256) void prep_fused(
    const float* __restrict__ x, unsigned short* __restrict__ x_bf,
    const float* __restrict__ Wqkv, unsigned short* __restrict__ wqkvT,
    const float* __restrict__ Wproj, unsigned short* __restrict__ wprojT) {
  __shared__ float tile[64][65];
  const int bid = blockIdx.x;
  const int t = threadIdx.x;

  if (bid < 4096) {
    const int i = bid * 256 + t;  // float4 index, n4 = 1048576
    float4 v = ((const float4*)x)[i];
    ushort4 o;
    o.x = f2bf(v.x); o.y = f2bf(v.y); o.z = f2bf(v.z); o.w = f2bf(v.w);
    ((ushort4*)x_bf)[i] = o;
    return;
  }

  const float* W;
  unsigned short* WT;
  int R, C, bx, by;
  if (bid < 4096 + 768) {
    const int b2 = bid - 4096;
    W = Wqkv; WT = wqkvT; R = D_; C = 3 * D_;
    by = b2 / 48; bx = b2 - by * 48;
  } else {
    const int b3 = bid - 4096 - 768;
    W = Wproj; WT = wprojT; R = D_; C = D_;
    by = b3 >> 4; bx = b3 & 15;
  }
  const int r0 = by * 64;
  const int c0 = bx * 64;
#pragma unroll
  for (int i = 0; i < 16; ++i) {
    int idx = t + i * 256;
    int rr = idx >> 6, cc = idx & 63;
    tile[rr][cc] = W[(size_t)(r0 + rr) * C + c0 + cc];
  }
  __syncthreads();
#pragma unroll
  for (int i = 0; i < 16; ++i) {
    int idx = t + i * 256;
    int rr = idx >> 6, cc = idx & 63;  // rr: row of WT (= col of W)
    WT[(size_t)(c0 + rr) * R + r0 + cc] = f2bf(tile[cc][rr]);
  }
}

// ------- bf16 GEMM, 128x128 tile, BK=64, T2 XOR-swizzled LDS (both sides) ---
// Staging: global_load_lds with LINEAR LDS dest; the source column is
// pre-swizzled (c ^ (row&7)*8), so logical LDS[r][c] = global[r][c^((r&7)*8)].
// Frag reads apply the same XOR -> 2-way banks instead of 16-way at 64-col
// stride. BK=64 halves the barrier-drain count per MFMA vs BK=32.
template <bool OUT_F32>
__global__ __launch_bounds__(256) void gemm_bias(
    const unsigned short* __restrict__ A, const unsigned short* __restrict__ Bt,
    const float* __restrict__ bias, void* __restrict__ Cout,
    int M, int N, int Kd) {
  __shared__ unsigned short As[128 * 64];  // 16 KB
  __shared__ unsigned short Bs[128 * 64];  // 16 KB
  const int t = threadIdx.x;
  const int w = t >> 6;
  const int l = t & 63;
  const int m0 = blockIdx.y * 128;
  const int n0 = blockIdx.x * 128;
  const int wr = w >> 1, wc = w & 1;

  f32x4 acc[4][4] = {};

  // staging geometry: granule g = i*256 + t -> row g>>3 (=i*32 + (t>>3)),
  // col-block g&7 (=t&7). Source col pre-swizzled by (row&7)*8.
  const int g_r = t >> 3;                                   // 0..31
  const int scol = ((t & 7) * 8) ^ ((g_r & 7) * 8);          // constant per thread
  char* asBase = (char*)As + w * 1024;
  char* bsBase = (char*)Bs + w * 1024;

  const int lr = l & 15;
  const int kq = (l >> 4) * 8;
  const int xr = (lr & 7) * 8;  // read-side XOR (row&7)*8, constant per thread

  const int KT = Kd >> 6;  // BK = 64
  for (int kt = 0; kt < KT; ++kt) {
    const int k0 = kt << 6;
    {
#pragma unroll
      for (int i = 0; i < 4; ++i)
        GLD_LDS16(A + (size_t)(m0 + i * 32 + g_r) * Kd + k0 + scol,
                  asBase + i * 4096);
#pragma unroll
      for (int i = 0; i < 4; ++i)
        GLD_LDS16(Bt + (size_t)(n0 + i * 32 + g_r) * Kd + k0 + scol,
                  bsBase + i * 4096);
    }
    __syncthreads();
    bf16x8v af[4][2], bfv[4][2];
#pragma unroll
    for (int m = 0; m < 4; ++m) {
      const int row = wr * 64 + m * 16 + lr;
#pragma unroll
      for (int ks = 0; ks < 2; ++ks)
        af[m][ks] = *(const bf16x8v*)&As[row * 64 + ((ks * 32 + kq) ^ xr)];
    }
#pragma unroll
    for (int n = 0; n < 4; ++n) {
      const int row = wc * 64 + n * 16 + lr;
#pragma unroll
      for (int ks = 0; ks < 2; ++ks)
        bfv[n][ks] = *(const bf16x8v*)&Bs[row * 64 + ((ks * 32 + kq) ^ xr)];
    }
#pragma unroll
    for (int m = 0; m < 4; ++m)
#pragma unroll
      for (int n = 0; n < 4; ++n)
#pragma unroll
        for (int ks = 0; ks < 2; ++ks)
          acc[m][n] = __builtin_amdgcn_mfma_f32_16x16x32_bf16(
              af[m][ks], bfv[n][ks], acc[m][n], 0, 0, 0);
    __syncthreads();
  }

  const int rbase = (l >> 4) * 4;
#pragma unroll
  for (int m = 0; m < 4; ++m) {
#pragma unroll
    for (int n = 0; n < 4; ++n) {
      const int gc = n0 + wc * 64 + n * 16 + lr;
      const float bv = bias[gc];
#pragma unroll
      for (int j = 0; j < 4; ++j) {
        const int gr = m0 + wr * 64 + m * 16 + rbase + j;
        float v = acc[m][n][j] + bv;
        if (OUT_F32)
          ((float*)Cout)[(size_t)gr * N + gc] = v;
        else
          ((unsigned short*)Cout)[(size_t)gr * N + gc] = f2bf(v);
      }
    }
  }
}

// ---------------- routed gather attention (v2-exact, 67us / 154MB config) ---
__global__ __launch_bounds__(256) void attn_kernel(
    const unsigned short* __restrict__ qkv, const int* __restrict__ routes,
    unsigned short* __restrict__ outp) {
  __shared__ float sc[16][68];       // padded: bank = (4*head + j) % 32
  __shared__ unsigned rtsoff[64];    // precomputed (b*S + r) * 3072
  __shared__ float pbuf[1024];       // cross-wave PV partials
  const int bs = blockIdx.x;
  const int b = bs >> 11;            // / S_
  const int s = bs & (S_ - 1);
  const int t = threadIdx.x;
  const int w = t >> 6, l = t & 63;
  const int kh2 = w >> 1, hh = w & 1;

  if (t < 64) {
    int r = routes[s * K_ + t];
    r = min(max(r, 0), S_ - 1);
    rtsoff[t] = (unsigned)(b * S_ + r) * 3072u;
  }
  __syncthreads();

  const unsigned colo = hh * 512 + l * 8;
  const int head = colo >> 6;
  const size_t rowbase = (size_t)bs * 3072;

  float q[8];
  {
    ushort8v u = *(const ushort8v*)(qkv + rowbase + colo);
#pragma unroll
    for (int i = 0; i < 8; ++i) q[i] = bf2f(u[i]) * 0.125f;  // 1/sqrt(64)
  }

  const unsigned kofs = 1024u + colo;
  const unsigned vofs = 2048u + colo;
  const int jbase = kh2 * 32;

  // scores
#pragma unroll 4
  for (int j2 = 0; j2 < 32; ++j2) {
    const int j = jbase + j2;
    ushort8v u = *(const ushort8v*)(qkv + (rtsoff[j] + kofs));
    float d = q[0] * bf2f(u[0]);
#pragma unroll
    for (int i = 1; i < 8; ++i) d += q[i] * bf2f(u[i]);
    d += __shfl_xor(d, 1);
    d += __shfl_xor(d, 2);
    d += __shfl_xor(d, 4);
    if ((l & 7) == 0) sc[head][j] = d;
  }
  __syncthreads();

  // softmax over K=64, 16 threads per head
  {
    const int h = t >> 4;
    const int l2 = t & 15;
    float v0 = sc[h][l2], v1 = sc[h][l2 + 16], v2 = sc[h][l2 + 32],
          v3 = sc[h][l2 + 48];
    float m = fmaxf(fmaxf(v0, v1), fmaxf(v2, v3));
    m = fmaxf(m, __shfl_xor(m, 1));
    m = fmaxf(m, __shfl_xor(m, 2));
    m = fmaxf(m, __shfl_xor(m, 4));
    m = fmaxf(m, __shfl_xor(m, 8));
    v0 = __expf(v0 - m); v1 = __expf(v1 - m);
    v2 = __expf(v2 - m); v3 = __expf(v3 - m);
    float ss = v0 + v1 + v2 + v3;
    ss += __shfl_xor(ss, 1);
    ss += __shfl_xor(ss, 2);
    ss += __shfl_xor(ss, 4);
    ss += __shfl_xor(ss, 8);
    float inv = 1.0f / ss;
    sc[h][l2] = v0 * inv;
    sc[h][l2 + 16] = v1 * inv;
    sc[h][l2 + 32] = v2 * inv;
    sc[h][l2 + 48] = v3 * inv;
  }
  __syncthreads();

  // PV
  float acc[8] = {};
#pragma unroll 4
  for (int j2 = 0; j2 < 32; ++j2) {
    const int j = jbase + j2;
    ushort8v u = *(const ushort8v*)(qkv + (rtsoff[j] + vofs));
    const float p = sc[head][j];
#pragma unroll
    for (int i = 0; i < 8; ++i) acc[i] += p * bf2f(u[i]);
  }

  if (kh2 == 1) {
    f32x4 a0 = {acc[0], acc[1], acc[2], acc[3]};
    f32x4 a1 = {acc[4], acc[5], acc[6], acc[7]};
    *(f32x4*)&pbuf[colo] = a0;
    *(f32x4*)&pbuf[colo + 4] = a1;
  }
  __syncthreads();
  if (kh2 == 0) {
    ushort8v o;
#pragma unroll
    for (int i = 0; i < 8; ++i) o[i] = f2bf(acc[i] + pbuf[colo + i]);
    *(ushort8v*)(outp + (size_t)bs * D_ + colo) = o;
  }
}

extern "C" void kernel_launch(void* const* d_in, const int* in_sizes, int n_in,
                              void* d_out, int out_size, void* d_ws,
                              size_t ws_size, hipStream_t stream) {
  const float* x = (const float*)d_in[0];
  const float* Wqkv = (const float*)d_in[1];
  const float* bqkv = (const float*)d_in[2];
  const float* Wproj = (const float*)d_in[3];
  const float* bproj = (const float*)d_in[4];
  const int* routes = (const int*)d_in[5];
  float* out = (float*)d_out;

  char* ws = (char*)d_ws;
  unsigned short* x_bf = (unsigned short*)(ws);                    //  8,388,608
  unsigned short* wqkvT = (unsigned short*)(ws + 8388608);         //  6,291,456
  unsigned short* wprojT = (unsigned short*)(ws + 14680064);       //  2,097,152
  unsigned short* qkv = (unsigned short*)(ws + 16777216);          // 25,165,824
  unsigned short* aout = (unsigned short*)(ws + 41943040);         //  8,388,608

  prep_fused<<<5120, 256, 0, stream>>>(x, x_bf, Wqkv, wqkvT, Wproj, wprojT);

  gemm_bias<false><<<dim3(3 * D_ / 128, B_ * S_ / 128), 256, 0, stream>>>(
      x_bf, wqkvT, bqkv, qkv, B_ * S_, 3 * D_, D_);
  attn_kernel<<<B_ * S_, 256, 0, stream>>>(qkv, routes, aout);
  gemm_bias<true><<<dim3(D_ / 128, B_ * S_ / 128), 256, 0, stream>>>(
      aout, wprojT, bproj, out, B_ * S_, D_, D_);
}